// Round 2
// baseline (719.950 us; speedup 1.0000x reference)
//
#include <hip/hip_runtime.h>

#define DD 64
#define CC 16

__global__ __launch_bounds__(256, 2)
void epmem_partial(const float* __restrict__ q,
                   const float* __restrict__ ctx,
                   const float* __restrict__ K,
                   const float* __restrict__ V,
                   const float* __restrict__ CT,
                   const float* __restrict__ TS,
                   const int* __restrict__ mask,
                   float* __restrict__ pl,
                   float* __restrict__ pacc,
                   int B, int M, int mper)
{
    const int b  = blockIdx.x * 256 + threadIdx.x;   // batch row owned by this lane
    const int ch = blockIdx.y;                       // M-chunk index
    const int m0 = ch * mper;
    int m1 = m0 + mper; if (m1 > M) m1 = M;

    // Q row and 0.5*context row in registers
    float qr[DD];
#pragma unroll
    for (int d = 0; d < DD; ++d) qr[d] = q[(size_t)b * DD + d];
    float cr[CC];
#pragma unroll
    for (int j = 0; j < CC; ++j) cr[j] = 0.5f * ctx[(size_t)b * CC + j];

    float acc[DD];
#pragma unroll
    for (int d = 0; d < DD; ++d) acc[d] = 0.0f;
    float lsum = 0.0f;

    for (int m = m0; m < m1; ++m) {
        // mask is identical for every lane (m is wave-uniform) -> whole-wave skip
        if (!mask[m]) continue;
        const float* __restrict__ Kr = K  + (size_t)m * DD;
        const float* __restrict__ Vr = V  + (size_t)m * DD;
        const float* __restrict__ Cr = CT + (size_t)m * CC;

        // time-decay bias (uniform per m)
        float s = 0.3f * expf(-0.1f * (1000.0f - TS[m]));
#pragma unroll
        for (int d = 0; d < DD; ++d) s += qr[d] * Kr[d];
#pragma unroll
        for (int j = 0; j < CC; ++j) s += cr[j] * Cr[j];

        // scores are O(4) in magnitude: exp without max-subtraction is safe in f32
        float p = __expf(s);
        lsum += p;
#pragma unroll
        for (int d = 0; d < DD; ++d) acc[d] += p * Vr[d];
    }

    // partials: pl[ch][b], pacc[ch][d][b]  (b fastest -> coalesced stores)
    pl[(size_t)ch * B + b] = lsum;
    float* pa = pacc + (size_t)ch * DD * B + b;
#pragma unroll
    for (int d = 0; d < DD; ++d) pa[(size_t)d * B] = acc[d];
}

__global__ __launch_bounds__(256)
void epmem_combine(const float* __restrict__ pl,
                   const float* __restrict__ pacc,
                   float* __restrict__ out,
                   int B, int split)
{
    // t ordered d-major so pacc reads are coalesced over b
    int t = blockIdx.x * 256 + threadIdx.x;
    if (t >= DD * B) return;
    int d = t / B;
    int b = t - d * B;
    float ls = 0.0f;
    for (int ch = 0; ch < split; ++ch) ls += pl[(size_t)ch * B + b];
    float v = 0.0f;
    for (int ch = 0; ch < split; ++ch) v += pacc[((size_t)ch * DD + d) * B + b];
    out[(size_t)b * DD + d] = v / ls;
}

extern "C" void kernel_launch(void* const* d_in, const int* in_sizes, int n_in,
                              void* d_out, int out_size, void* d_ws, size_t ws_size,
                              hipStream_t stream)
{
    const float* q   = (const float*)d_in[0];
    const float* ctx = (const float*)d_in[1];
    const float* K   = (const float*)d_in[2];
    const float* V   = (const float*)d_in[3];
    const float* CT  = (const float*)d_in[4];
    const float* TS  = (const float*)d_in[5];
    const int*   mask = (const int*)d_in[6];

    const int B = in_sizes[0] / DD;   // 1024
    const int M = in_sizes[2] / DD;   // 65536

    // split M across blocks; partial buffers sized from ws
    size_t chunk_bytes = (size_t)B * (DD + 1) * sizeof(float);
    int split = (int)(ws_size / chunk_bytes);
    if (split > 128) split = 128;
    if (split < 1)  split = 1;
    int mper = (M + split - 1) / split;

    float* pl   = (float*)d_ws;                  // [split][B]
    float* pacc = pl + (size_t)split * B;        // [split][DD][B]

    dim3 grid1(B / 256, split);
    epmem_partial<<<grid1, 256, 0, stream>>>(q, ctx, K, V, CT, TS, mask,
                                             pl, pacc, B, M, mper);

    int nt = DD * B;
    epmem_combine<<<(nt + 255) / 256, 256, 0, stream>>>(pl, pacc, (float*)d_out,
                                                        B, split);
}

// Round 3
// 395.890 us; speedup vs baseline: 1.8186x; 1.8186x over previous
//
#include <hip/hip_runtime.h>

#define DD 64
#define CC 16

// ---------- compaction: count -> scan -> scatter (deterministic, no atomics) ----------

__global__ __launch_bounds__(256)
void k_count(const int* __restrict__ mask, int* __restrict__ blockCount, int M)
{
    int t = threadIdx.x;
    int m = blockIdx.x * 256 + t;
    int active = (m < M) && mask[m];
    unsigned long long bal = __ballot(active);
    __shared__ int wc[4];
    if ((t & 63) == 0) wc[t >> 6] = __popcll(bal);
    __syncthreads();
    if (t == 0) blockCount[blockIdx.x] = wc[0] + wc[1] + wc[2] + wc[3];
}

__global__ void k_scan(const int* __restrict__ blockCount, int* __restrict__ blockOff,
                       int* __restrict__ MaPtr, int nb)
{
    if (threadIdx.x == 0 && blockIdx.x == 0) {
        int s = 0;
        for (int i = 0; i < nb; ++i) { blockOff[i] = s; s += blockCount[i]; }
        *MaPtr = s;
    }
}

__global__ __launch_bounds__(256)
void k_scatter(const int* __restrict__ mask, const float* __restrict__ TS,
               const int* __restrict__ blockOff,
               int* __restrict__ idxc, float* __restrict__ biasc, int M)
{
    int t = threadIdx.x;
    int m = blockIdx.x * 256 + t;
    int active = (m < M) && mask[m];
    unsigned long long bal = __ballot(active);
    int lane = t & 63, wid = t >> 6;
    __shared__ int wc[4];
    if (lane == 0) wc[wid] = __popcll(bal);
    __syncthreads();
    int base = blockOff[blockIdx.x];
    for (int w = 0; w < wid; ++w) base += wc[w];
    int rank = __popcll(bal & ((1ull << lane) - 1ull));
    if (active) {
        int dst = base + rank;
        idxc[dst]  = m;
        biasc[dst] = 0.3f * __expf(-0.1f * (1000.0f - TS[m]));
    }
}

// ---------- main: branch-free flash-decode over compacted slots ----------

__global__ __launch_bounds__(256, 2)
void epmem_partial(const float* __restrict__ q,
                   const float* __restrict__ ctx,
                   const float* __restrict__ K,
                   const float* __restrict__ V,
                   const float* __restrict__ CT,
                   const int* __restrict__ idxc,
                   const float* __restrict__ biasc,
                   const int* __restrict__ MaPtr,
                   float* __restrict__ pl,
                   float* __restrict__ pacc,
                   int B, int split)
{
    const int b  = blockIdx.x * 256 + threadIdx.x;
    const int ch = blockIdx.y;
    const int Ma = *MaPtr;
    const int per = (Ma + split - 1) / split;
    const int r0 = ch * per;
    int r1 = r0 + per; if (r1 > Ma) r1 = Ma;

    float qr[DD];
#pragma unroll
    for (int d = 0; d < DD; ++d) qr[d] = q[(size_t)b * DD + d];
    float cr[CC];
#pragma unroll
    for (int j = 0; j < CC; ++j) cr[j] = 0.5f * ctx[(size_t)b * CC + j];

    float acc[DD];
#pragma unroll
    for (int d = 0; d < DD; ++d) acc[d] = 0.0f;
    float lsum = 0.0f;

    int r = r0;
    for (; r + 1 < r1; r += 2) {
        const int ma = idxc[r], mb = idxc[r + 1];
        const float biasa = biasc[r], biasb = biasc[r + 1];
        const float4* __restrict__ Ka = (const float4*)(K  + (size_t)ma * DD);
        const float4* __restrict__ Kb = (const float4*)(K  + (size_t)mb * DD);
        const float4* __restrict__ Ca = (const float4*)(CT + (size_t)ma * CC);
        const float4* __restrict__ Cb = (const float4*)(CT + (size_t)mb * CC);
        const float4* __restrict__ Va = (const float4*)(V  + (size_t)ma * DD);
        const float4* __restrict__ Vb = (const float4*)(V  + (size_t)mb * DD);

        float sa0 = biasa, sa1 = 0.0f, sb0 = biasb, sb1 = 0.0f;
#pragma unroll
        for (int i = 0; i < 16; ++i) {
            float4 ka = Ka[i], kb = Kb[i];
            sa0 = fmaf(ka.x, qr[4*i+0], sa0);
            sa1 = fmaf(ka.y, qr[4*i+1], sa1);
            sa0 = fmaf(ka.z, qr[4*i+2], sa0);
            sa1 = fmaf(ka.w, qr[4*i+3], sa1);
            sb0 = fmaf(kb.x, qr[4*i+0], sb0);
            sb1 = fmaf(kb.y, qr[4*i+1], sb1);
            sb0 = fmaf(kb.z, qr[4*i+2], sb0);
            sb1 = fmaf(kb.w, qr[4*i+3], sb1);
        }
#pragma unroll
        for (int i = 0; i < 4; ++i) {
            float4 ca = Ca[i], cb = Cb[i];
            sa0 = fmaf(ca.x, cr[4*i+0], sa0);
            sa1 = fmaf(ca.y, cr[4*i+1], sa1);
            sa0 = fmaf(ca.z, cr[4*i+2], sa0);
            sa1 = fmaf(ca.w, cr[4*i+3], sa1);
            sb0 = fmaf(cb.x, cr[4*i+0], sb0);
            sb1 = fmaf(cb.y, cr[4*i+1], sb1);
            sb0 = fmaf(cb.z, cr[4*i+2], sb0);
            sb1 = fmaf(cb.w, cr[4*i+3], sb1);
        }
        const float pa = __expf(sa0 + sa1);
        const float pb = __expf(sb0 + sb1);
        lsum += pa + pb;
#pragma unroll
        for (int i = 0; i < 16; ++i) {
            float4 va = Va[i], vb = Vb[i];
            acc[4*i+0] = fmaf(pa, va.x, acc[4*i+0]);
            acc[4*i+1] = fmaf(pa, va.y, acc[4*i+1]);
            acc[4*i+2] = fmaf(pa, va.z, acc[4*i+2]);
            acc[4*i+3] = fmaf(pa, va.w, acc[4*i+3]);
            acc[4*i+0] = fmaf(pb, vb.x, acc[4*i+0]);
            acc[4*i+1] = fmaf(pb, vb.y, acc[4*i+1]);
            acc[4*i+2] = fmaf(pb, vb.z, acc[4*i+2]);
            acc[4*i+3] = fmaf(pb, vb.w, acc[4*i+3]);
        }
    }
    // tail (at most 1)
    for (; r < r1; ++r) {
        const int m = idxc[r];
        const float4* __restrict__ Ka = (const float4*)(K  + (size_t)m * DD);
        const float4* __restrict__ Ca = (const float4*)(CT + (size_t)m * CC);
        const float4* __restrict__ Va = (const float4*)(V  + (size_t)m * DD);
        float s0 = biasc[r], s1 = 0.0f;
#pragma unroll
        for (int i = 0; i < 16; ++i) {
            float4 ka = Ka[i];
            s0 = fmaf(ka.x, qr[4*i+0], s0);
            s1 = fmaf(ka.y, qr[4*i+1], s1);
            s0 = fmaf(ka.z, qr[4*i+2], s0);
            s1 = fmaf(ka.w, qr[4*i+3], s1);
        }
#pragma unroll
        for (int i = 0; i < 4; ++i) {
            float4 ca = Ca[i];
            s0 = fmaf(ca.x, cr[4*i+0], s0);
            s1 = fmaf(ca.y, cr[4*i+1], s1);
            s0 = fmaf(ca.z, cr[4*i+2], s0);
            s1 = fmaf(ca.w, cr[4*i+3], s1);
        }
        const float p = __expf(s0 + s1);
        lsum += p;
#pragma unroll
        for (int i = 0; i < 16; ++i) {
            float4 va = Va[i];
            acc[4*i+0] = fmaf(p, va.x, acc[4*i+0]);
            acc[4*i+1] = fmaf(p, va.y, acc[4*i+1]);
            acc[4*i+2] = fmaf(p, va.z, acc[4*i+2]);
            acc[4*i+3] = fmaf(p, va.w, acc[4*i+3]);
        }
    }

    pl[(size_t)ch * B + b] = lsum;
    float* pa_ = pacc + (size_t)ch * DD * B + b;
#pragma unroll
    for (int d = 0; d < DD; ++d) pa_[(size_t)d * B] = acc[d];
}

__global__ __launch_bounds__(256)
void epmem_combine(const float* __restrict__ pl,
                   const float* __restrict__ pacc,
                   float* __restrict__ out,
                   int B, int split)
{
    int t = blockIdx.x * 256 + threadIdx.x;
    if (t >= DD * B) return;
    int d = t / B;
    int b = t - d * B;
    float ls = 0.0f;
    for (int ch = 0; ch < split; ++ch) ls += pl[(size_t)ch * B + b];
    float v = 0.0f;
    for (int ch = 0; ch < split; ++ch) v += pacc[((size_t)ch * DD + d) * B + b];
    out[(size_t)b * DD + d] = v / ls;
}

extern "C" void kernel_launch(void* const* d_in, const int* in_sizes, int n_in,
                              void* d_out, int out_size, void* d_ws, size_t ws_size,
                              hipStream_t stream)
{
    const float* q    = (const float*)d_in[0];
    const float* ctx  = (const float*)d_in[1];
    const float* K    = (const float*)d_in[2];
    const float* V    = (const float*)d_in[3];
    const float* CT   = (const float*)d_in[4];
    const float* TS   = (const float*)d_in[5];
    const int*   mask = (const int*)d_in[6];

    const int B = in_sizes[0] / DD;   // 1024
    const int M = in_sizes[2] / DD;   // 65536
    const int nb = (M + 255) / 256;   // 256 count/scatter blocks

    // ws layout (bytes):
    // [0,4)          Ma
    // [4096, +nb*4)  blockCount
    // [8192, +nb*4)  blockOff
    // [12288, +M*4)  idxc
    // [12288+M*4, +M*4) biasc
    // then pl [split][B], pacc [split][DD][B]
    char* w = (char*)d_ws;
    int*   MaPtr      = (int*)(w);
    int*   blockCount = (int*)(w + 4096);
    int*   blockOff   = (int*)(w + 8192);
    int*   idxc       = (int*)(w + 12288);
    float* biasc      = (float*)(w + 12288 + (size_t)M * 4);
    size_t fixed      = 12288 + (size_t)M * 8;

    size_t chunk_bytes = (size_t)B * (DD + 1) * sizeof(float);
    long long avail = (long long)ws_size - (long long)fixed;
    int split = (int)(avail / (long long)chunk_bytes);
    if (split > 128) split = 128;
    if (split < 1)  split = 1;

    float* pl   = (float*)(w + fixed);
    float* pacc = pl + (size_t)split * B;

    k_count  <<<nb, 256, 0, stream>>>(mask, blockCount, M);
    k_scan   <<<1, 64, 0, stream>>>(blockCount, blockOff, MaPtr, nb);
    k_scatter<<<nb, 256, 0, stream>>>(mask, TS, blockOff, idxc, biasc, M);

    dim3 grid1(B / 256, split);
    epmem_partial<<<grid1, 256, 0, stream>>>(q, ctx, K, V, CT, idxc, biasc, MaPtr,
                                             pl, pacc, B, split);

    int nt = DD * B;
    epmem_combine<<<(nt + 255) / 256, 256, 0, stream>>>(pl, pacc, (float*)d_out,
                                                        B, split);
}

// Round 4
// 167.059 us; speedup vs baseline: 4.3096x; 2.3698x over previous
//
#include <hip/hip_runtime.h>

typedef float f32x4 __attribute__((ext_vector_type(4)));
typedef __bf16 bf16x8 __attribute__((ext_vector_type(8)));

#define MTOT 65536
#define BTOT 1024
#define DD 64

__device__ __forceinline__ unsigned short f2bf(float f) {
    unsigned int u = __float_as_uint(f);
    unsigned int r = (u + 0x7FFFu + ((u >> 16) & 1u)) >> 16;
    return (unsigned short)r;
}

// ---------------- precompute ----------------

__global__ __launch_bounds__(256)
void prep_qc(const float* __restrict__ q, const float* __restrict__ ctx,
             unsigned short* __restrict__ Qc)
{
    int gid = blockIdx.x * 256 + threadIdx.x;   // 1024*96
    if (gid >= BTOT * 96) return;
    int b = gid / 96, c = gid - b * 96;
    float v;
    if (c < 64)       v = q[b * 64 + c];
    else if (c < 80)  v = 0.5f * ctx[b * 16 + (c - 64)];
    else if (c == 80) v = 1.0f;
    else              v = 0.0f;
    Qc[gid] = f2bf(v);
}

__global__ __launch_bounds__(192)
void prep_kc(const float* __restrict__ K, const float* __restrict__ CT,
             const float* __restrict__ TS, const int* __restrict__ mask,
             unsigned short* __restrict__ KC)
{
    int gid = blockIdx.x * 192 + threadIdx.x;   // 65536*96 exact
    int m = gid / 96, c = gid - m * 96;
    float v;
    if (c < 64)       v = K[(size_t)m * 64 + c];
    else if (c < 80)  v = CT[(size_t)m * 16 + (c - 64)];
    else if (c == 80) v = mask[m] ? 0.3f * __expf(-0.1f * (1000.0f - TS[m])) : -100.0f;
    else              v = 0.0f;
    KC[gid] = f2bf(v);
}

__global__ __launch_bounds__(256)
void prep_vt(const float* __restrict__ V, unsigned short* __restrict__ Vt)
{
    __shared__ unsigned short L[64][66];
    int m0 = blockIdx.x * 64;
    int t = threadIdx.x;
#pragma unroll
    for (int i = 0; i < 16; ++i) {
        int j = t + 256 * i;           // 0..4095
        int mi = j >> 6, di = j & 63;
        L[mi][di] = f2bf(V[(size_t)(m0 + mi) * 64 + di]);
    }
    __syncthreads();
    int d = t >> 2, mc = (t & 3) << 4;
    unsigned int u[8];
#pragma unroll
    for (int i = 0; i < 8; ++i)
        u[i] = (unsigned int)L[mc + 2 * i][d] | ((unsigned int)L[mc + 2 * i + 1][d] << 16);
    unsigned short* dst = Vt + (size_t)d * MTOT + m0 + mc;
    uint4 a = {u[0], u[1], u[2], u[3]};
    uint4 b4 = {u[4], u[5], u[6], u[7]};
    *(uint4*)(dst) = a;
    *(uint4*)(dst + 8) = b4;
}

// ---------------- main flash-MFMA kernel ----------------

__global__ __launch_bounds__(256, 2)
void epmem_mfma(const unsigned short* __restrict__ Qc,
                const unsigned short* __restrict__ KC,
                const unsigned short* __restrict__ Vt,
                float* __restrict__ pl,
                float* __restrict__ pacc,
                int mper, int NB)
{
    __shared__ __align__(16) unsigned short Pbuf[4][16][40];

    const int tid = threadIdx.x;
    const int w = tid >> 6, lane = tid & 63;
    const int l15 = lane & 15, g = lane >> 4;

    // XCD-bijective swizzle: consecutive o (= ch*16 + rtile) per XCD
    int bid = blockIdx.x;
    int o = (bid & 7) * (NB >> 3) + (bid >> 3);
    const int ch = o >> 4, rtile = o & 15;
    const int rbase = rtile * 64 + w * 16;

    // A-frags for S: Qc rows (row = rbase + l15, k = g*8 + e per 32-k step)
    const unsigned short* qrow = Qc + (size_t)(rbase + l15) * 96 + g * 8;
    const bf16x8 qf0 = *reinterpret_cast<const bf16x8*>(qrow);
    const bf16x8 qf1 = *reinterpret_cast<const bf16x8*>(qrow + 32);
    const bf16x8 qf2 = *reinterpret_cast<const bf16x8*>(qrow + 64);

    const int m0 = ch * mper;
    int m1 = m0 + mper; if (m1 > MTOT) m1 = MTOT;

    f32x4 acc0 = {0,0,0,0}, acc1 = {0,0,0,0}, acc2 = {0,0,0,0}, acc3 = {0,0,0,0};
    f32x4 lsum = {0,0,0,0};

    const unsigned short* kc0 = KC + (size_t)(m0 + l15) * 96 + g * 8;
    const unsigned short* vt0 = Vt + (size_t)l15 * MTOT + m0 + g * 8;

    for (int m = m0; m < m1; m += 32) {
        // B-frags: KC^T (lane: col m' = m + 16s + l15, k = g*8+e)
        bf16x8 k00 = *reinterpret_cast<const bf16x8*>(kc0);
        bf16x8 k01 = *reinterpret_cast<const bf16x8*>(kc0 + 32);
        bf16x8 k02 = *reinterpret_cast<const bf16x8*>(kc0 + 64);
        const unsigned short* kc1 = kc0 + 16 * 96;
        bf16x8 k10 = *reinterpret_cast<const bf16x8*>(kc1);
        bf16x8 k11 = *reinterpret_cast<const bf16x8*>(kc1 + 32);
        bf16x8 k12 = *reinterpret_cast<const bf16x8*>(kc1 + 64);

        f32x4 S0 = {0,0,0,0}, S1 = {0,0,0,0};
        S0 = __builtin_amdgcn_mfma_f32_16x16x32_bf16(qf0, k00, S0, 0, 0, 0);
        S0 = __builtin_amdgcn_mfma_f32_16x16x32_bf16(qf1, k01, S0, 0, 0, 0);
        S0 = __builtin_amdgcn_mfma_f32_16x16x32_bf16(qf2, k02, S0, 0, 0, 0);
        S1 = __builtin_amdgcn_mfma_f32_16x16x32_bf16(qf0, k10, S1, 0, 0, 0);
        S1 = __builtin_amdgcn_mfma_f32_16x16x32_bf16(qf1, k11, S1, 0, 0, 0);
        S1 = __builtin_amdgcn_mfma_f32_16x16x32_bf16(qf2, k12, S1, 0, 0, 0);

        // p = exp(S) (bias+mask already folded into S via column 80)
        // S C/D layout: lane holds col m' = l15 (per subtile), rows b = g*4+r
#pragma unroll
        for (int r = 0; r < 4; ++r) {
            float p0 = __expf(S0[r]);
            float p1 = __expf(S1[r]);
            lsum[r] += p0 + p1;
            Pbuf[w][g * 4 + r][l15]      = f2bf(p0);
            Pbuf[w][g * 4 + r][16 + l15] = f2bf(p1);
        }

        // PV: A-frag P[b][m'] (lane: row=l15, k=g*8+e) — 16B contiguous
        bf16x8 pa = *reinterpret_cast<const bf16x8*>(&Pbuf[w][l15][g * 8]);
        // B-frags: Vt rows (lane: col d = dsub*16 + l15, k = m' = g*8+e)
        bf16x8 v0 = *reinterpret_cast<const bf16x8*>(vt0);
        bf16x8 v1 = *reinterpret_cast<const bf16x8*>(vt0 + (size_t)16 * MTOT);
        bf16x8 v2 = *reinterpret_cast<const bf16x8*>(vt0 + (size_t)32 * MTOT);
        bf16x8 v3 = *reinterpret_cast<const bf16x8*>(vt0 + (size_t)48 * MTOT);

        acc0 = __builtin_amdgcn_mfma_f32_16x16x32_bf16(pa, v0, acc0, 0, 0, 0);
        acc1 = __builtin_amdgcn_mfma_f32_16x16x32_bf16(pa, v1, acc1, 0, 0, 0);
        acc2 = __builtin_amdgcn_mfma_f32_16x16x32_bf16(pa, v2, acc2, 0, 0, 0);
        acc3 = __builtin_amdgcn_mfma_f32_16x16x32_bf16(pa, v3, acc3, 0, 0, 0);

        kc0 += 32 * 96;
        vt0 += 32;
    }

    // lsum: reduce over the 16 lanes of each g-group (cols of the S tile)
#pragma unroll
    for (int r = 0; r < 4; ++r) {
        float v = lsum[r];
        v += __shfl_xor(v, 1, 16);
        v += __shfl_xor(v, 2, 16);
        v += __shfl_xor(v, 4, 16);
        v += __shfl_xor(v, 8, 16);
        lsum[r] = v;
    }
    if (l15 == 0) {
        f32x4 pls = {lsum[0], lsum[1], lsum[2], lsum[3]};
        *reinterpret_cast<f32x4*>(pl + (size_t)ch * BTOT + rbase + g * 4) = pls;
    }

    // acc stores: lane holds d = dsub*16+l15, b = rbase + g*4 + r (r = reg)
    {
        float* base = pacc + ((size_t)ch * DD) * BTOT + rbase + g * 4;
        *reinterpret_cast<f32x4*>(base + (size_t)(0 * 16 + l15) * BTOT) = acc0;
        *reinterpret_cast<f32x4*>(base + (size_t)(16 + l15) * BTOT)     = acc1;
        *reinterpret_cast<f32x4*>(base + (size_t)(32 + l15) * BTOT)     = acc2;
        *reinterpret_cast<f32x4*>(base + (size_t)(48 + l15) * BTOT)     = acc3;
    }
}

// ---------------- combine ----------------

__global__ __launch_bounds__(256)
void epmem_combine(const float* __restrict__ pl,
                   const float* __restrict__ pacc,
                   float* __restrict__ out,
                   int split)
{
    int t = blockIdx.x * 256 + threadIdx.x;
    if (t >= DD * BTOT) return;
    int d = t >> 10;           // /1024
    int b = t & 1023;
    float ls = 0.0f;
    for (int ch = 0; ch < split; ++ch) ls += pl[(size_t)ch * BTOT + b];
    float v = 0.0f;
    for (int ch = 0; ch < split; ++ch) v += pacc[((size_t)ch * DD + d) * BTOT + b];
    out[(size_t)b * DD + d] = v / ls;
}

extern "C" void kernel_launch(void* const* d_in, const int* in_sizes, int n_in,
                              void* d_out, int out_size, void* d_ws, size_t ws_size,
                              hipStream_t stream)
{
    const float* q    = (const float*)d_in[0];
    const float* ctx  = (const float*)d_in[1];
    const float* K    = (const float*)d_in[2];
    const float* V    = (const float*)d_in[3];
    const float* CT   = (const float*)d_in[4];
    const float* TS   = (const float*)d_in[5];
    const int*   mask = (const int*)d_in[6];

    // ws layout
    char* wsb = (char*)d_ws;
    unsigned short* Qc = (unsigned short*)(wsb);                         // 1024*96*2   = 196608
    unsigned short* KC = (unsigned short*)(wsb + 196608);                // 65536*96*2  = 12582912
    unsigned short* Vt = (unsigned short*)(wsb + 196608 + 12582912);     // 64*65536*2  = 8388608
    size_t fixed = 196608 + 12582912 + 8388608;                          // 21168128

    size_t chunk = (size_t)BTOT * (DD + 1) * sizeof(float);              // 266240
    int SPLIT = (int)((ws_size - fixed) / chunk);
    if (SPLIT > 64) SPLIT = 64;
    SPLIT &= ~7;                       // multiple of 8 (swizzle + sizing)
    if (SPLIT < 8) SPLIT = 8;

    float* pl   = (float*)(wsb + fixed);                 // [SPLIT][1024]
    float* pacc = pl + (size_t)SPLIT * BTOT;             // [SPLIT][64][1024]

    int mper = ((MTOT + SPLIT - 1) / SPLIT + 31) & ~31;  // multiple of 32

    prep_qc<<<(BTOT * 96 + 255) / 256, 256, 0, stream>>>(q, ctx, Qc);
    prep_kc<<<(MTOT * 96) / 192, 192, 0, stream>>>(K, CT, TS, mask, KC);
    prep_vt<<<MTOT / 64, 256, 0, stream>>>(V, Vt);

    int NB = 16 * SPLIT;
    epmem_mfma<<<NB, 256, 0, stream>>>(Qc, KC, Vt, pl, pacc, mper, NB);

    epmem_combine<<<(DD * BTOT + 255) / 256, 256, 0, stream>>>(pl, pacc, (float*)d_out, SPLIT);
}

// Round 5
// 119.728 us; speedup vs baseline: 6.0132x; 1.3953x over previous
//
#include <hip/hip_runtime.h>

typedef float f32x4 __attribute__((ext_vector_type(4)));
typedef __bf16 bf16x8 __attribute__((ext_vector_type(8)));

#define MTOT 65536
#define BTOT 1024
#define DD 64

__device__ __forceinline__ unsigned short f2bf(float f) {
    unsigned int u = __float_as_uint(f);
    unsigned int r = (u + 0x7FFFu + ((u >> 16) & 1u)) >> 16;
    return (unsigned short)r;
}

__device__ __forceinline__ bf16x8 ldb8(const unsigned short* p) {
    return *reinterpret_cast<const bf16x8*>(p);
}

#define MFMA __builtin_amdgcn_mfma_f32_16x16x32_bf16

// ---------------- precompute ----------------

__global__ __launch_bounds__(256)
void prep_qc(const float* __restrict__ q, const float* __restrict__ ctx,
             unsigned short* __restrict__ Qc)
{
    int gid = blockIdx.x * 256 + threadIdx.x;   // 1024*96
    if (gid >= BTOT * 96) return;
    int b = gid / 96, c = gid - b * 96;
    float v;
    if (c < 64)       v = q[b * 64 + c];
    else if (c < 80)  v = 0.5f * ctx[b * 16 + (c - 64)];
    else if (c == 80) v = 1.0f;
    else              v = 0.0f;
    Qc[gid] = f2bf(v);
}

__global__ __launch_bounds__(192)
void prep_kc(const float* __restrict__ K, const float* __restrict__ CT,
             const float* __restrict__ TS, const int* __restrict__ mask,
             unsigned short* __restrict__ KC)
{
    int gid = blockIdx.x * 192 + threadIdx.x;   // 65536*96 exact
    int m = gid / 96, c = gid - m * 96;
    float v;
    if (c < 64)       v = K[(size_t)m * 64 + c];
    else if (c < 80)  v = CT[(size_t)m * 16 + (c - 64)];
    else if (c == 80) v = mask[m] ? 0.3f * __expf(-0.1f * (1000.0f - TS[m])) : -100.0f;
    else              v = 0.0f;
    KC[gid] = f2bf(v);
}

__global__ __launch_bounds__(256)
void prep_vt(const float* __restrict__ V, unsigned short* __restrict__ Vt)
{
    __shared__ unsigned short L[64][66];
    int m0 = blockIdx.x * 64;
    int t = threadIdx.x;
#pragma unroll
    for (int i = 0; i < 16; ++i) {
        int j = t + 256 * i;           // 0..4095
        int mi = j >> 6, di = j & 63;
        L[mi][di] = f2bf(V[(size_t)(m0 + mi) * 64 + di]);
    }
    __syncthreads();
    int d = t >> 2, mc = (t & 3) << 4;
    unsigned int u[8];
#pragma unroll
    for (int i = 0; i < 8; ++i)
        u[i] = (unsigned int)L[mc + 2 * i][d] | ((unsigned int)L[mc + 2 * i + 1][d] << 16);
    unsigned short* dst = Vt + (size_t)d * MTOT + m0 + mc;
    uint4 a = {u[0], u[1], u[2], u[3]};
    uint4 b4 = {u[4], u[5], u[6], u[7]};
    *(uint4*)(dst) = a;
    *(uint4*)(dst + 8) = b4;
}

// ---------------- main flash-MFMA kernel (reg-dbuf, 32 rows/wave) ----------------

__global__ __launch_bounds__(256, 2)
void epmem_mfma(const unsigned short* __restrict__ Qc,
                const unsigned short* __restrict__ KC,
                const unsigned short* __restrict__ Vt,
                float* __restrict__ pl,
                float* __restrict__ pacc,
                int mper, int NB)
{
    __shared__ __align__(16) __bf16 Pbuf[4][32][40];

    const int tid = threadIdx.x;
    const int w = tid >> 6, lane = tid & 63;
    const int l15 = lane & 15, g = lane >> 4;

    // XCD-bijective swizzle (NB multiple of 8): consecutive o per XCD
    int bid = blockIdx.x;
    int o = (bid & 7) * (NB >> 3) + (bid >> 3);
    const int ch = o >> 3, rtile = o & 7;
    const int rbase = rtile * 128 + w * 32;

    // Q A-frags for 2 row-fragments (rows rbase+l15, rbase+16+l15)
    const unsigned short* q0 = Qc + (size_t)(rbase + l15) * 96 + g * 8;
    const bf16x8 qf00 = ldb8(q0), qf01 = ldb8(q0 + 32), qf02 = ldb8(q0 + 64);
    const unsigned short* q1 = q0 + 16 * 96;
    const bf16x8 qf10 = ldb8(q1), qf11 = ldb8(q1 + 32), qf12 = ldb8(q1 + 64);

    const int m0 = ch * mper;
    int m1 = m0 + mper; if (m1 > MTOT) m1 = MTOT;

    const unsigned short* kc = KC + (size_t)(m0 + l15) * 96 + g * 8;
    const unsigned short* vt = Vt + (size_t)l15 * MTOT + m0 + g * 8;

    f32x4 a00 = {0,0,0,0}, a01 = {0,0,0,0}, a02 = {0,0,0,0}, a03 = {0,0,0,0};
    f32x4 a10 = {0,0,0,0}, a11 = {0,0,0,0}, a12 = {0,0,0,0}, a13 = {0,0,0,0};
    f32x4 ls0 = {0,0,0,0}, ls1 = {0,0,0,0};

    // prologue: current fragments
    bf16x8 k0 = ldb8(kc),          k1 = ldb8(kc + 32),          k2 = ldb8(kc + 64);
    bf16x8 k3 = ldb8(kc + 16*96),  k4 = ldb8(kc + 16*96 + 32),  k5 = ldb8(kc + 16*96 + 64);
    bf16x8 v0 = ldb8(vt),                    v1 = ldb8(vt + (size_t)16 * MTOT);
    bf16x8 v2 = ldb8(vt + (size_t)32 * MTOT), v3 = ldb8(vt + (size_t)48 * MTOT);

    for (int m = m0; m < m1; m += 32) {
        kc += 32 * 96; vt += 32;
        // issue next-iteration loads FIRST (KC padded 32 rows; Vt overrun lands in pl — unused)
        bf16x8 nk0 = ldb8(kc),         nk1 = ldb8(kc + 32),         nk2 = ldb8(kc + 64);
        bf16x8 nk3 = ldb8(kc + 16*96), nk4 = ldb8(kc + 16*96 + 32), nk5 = ldb8(kc + 16*96 + 64);
        bf16x8 nv0 = ldb8(vt),                     nv1 = ldb8(vt + (size_t)16 * MTOT);
        bf16x8 nv2 = ldb8(vt + (size_t)32 * MTOT), nv3 = ldb8(vt + (size_t)48 * MTOT);

        f32x4 S00 = {0,0,0,0}, S01 = {0,0,0,0}, S10 = {0,0,0,0}, S11 = {0,0,0,0};
        S00 = MFMA(qf00, k0, S00, 0,0,0); S00 = MFMA(qf01, k1, S00, 0,0,0); S00 = MFMA(qf02, k2, S00, 0,0,0);
        S01 = MFMA(qf00, k3, S01, 0,0,0); S01 = MFMA(qf01, k4, S01, 0,0,0); S01 = MFMA(qf02, k5, S01, 0,0,0);
        S10 = MFMA(qf10, k0, S10, 0,0,0); S10 = MFMA(qf11, k1, S10, 0,0,0); S10 = MFMA(qf12, k2, S10, 0,0,0);
        S11 = MFMA(qf10, k3, S11, 0,0,0); S11 = MFMA(qf11, k4, S11, 0,0,0); S11 = MFMA(qf12, k5, S11, 0,0,0);

#pragma unroll
        for (int r = 0; r < 4; ++r) {
            float p00 = __expf(S00[r]), p01 = __expf(S01[r]);
            float p10 = __expf(S10[r]), p11 = __expf(S11[r]);
            ls0[r] += p00 + p01;
            ls1[r] += p10 + p11;
            Pbuf[w][g * 4 + r][l15]           = (__bf16)p00;
            Pbuf[w][g * 4 + r][16 + l15]      = (__bf16)p01;
            Pbuf[w][16 + g * 4 + r][l15]      = (__bf16)p10;
            Pbuf[w][16 + g * 4 + r][16 + l15] = (__bf16)p11;
        }

        bf16x8 pa0 = *reinterpret_cast<const bf16x8*>(&Pbuf[w][l15][g * 8]);
        bf16x8 pa1 = *reinterpret_cast<const bf16x8*>(&Pbuf[w][16 + l15][g * 8]);

        a00 = MFMA(pa0, v0, a00, 0,0,0); a01 = MFMA(pa0, v1, a01, 0,0,0);
        a02 = MFMA(pa0, v2, a02, 0,0,0); a03 = MFMA(pa0, v3, a03, 0,0,0);
        a10 = MFMA(pa1, v0, a10, 0,0,0); a11 = MFMA(pa1, v1, a11, 0,0,0);
        a12 = MFMA(pa1, v2, a12, 0,0,0); a13 = MFMA(pa1, v3, a13, 0,0,0);

        k0 = nk0; k1 = nk1; k2 = nk2; k3 = nk3; k4 = nk4; k5 = nk5;
        v0 = nv0; v1 = nv1; v2 = nv2; v3 = nv3;
    }

    // lsum: reduce over the 16 m-col lanes
#pragma unroll
    for (int r = 0; r < 4; ++r) {
        float x = ls0[r];
        x += __shfl_xor(x, 1, 16); x += __shfl_xor(x, 2, 16);
        x += __shfl_xor(x, 4, 16); x += __shfl_xor(x, 8, 16);
        ls0[r] = x;
        float y = ls1[r];
        y += __shfl_xor(y, 1, 16); y += __shfl_xor(y, 2, 16);
        y += __shfl_xor(y, 4, 16); y += __shfl_xor(y, 8, 16);
        ls1[r] = y;
    }
    if (l15 == 0) {
        f32x4 s0 = {ls0[0], ls0[1], ls0[2], ls0[3]};
        f32x4 s1 = {ls1[0], ls1[1], ls1[2], ls1[3]};
        *reinterpret_cast<f32x4*>(pl + (size_t)ch * BTOT + rbase + g * 4)      = s0;
        *reinterpret_cast<f32x4*>(pl + (size_t)ch * BTOT + rbase + 16 + g * 4) = s1;
    }

    // acc stores: lane holds d = d4*16+l15, b = rbase + f*16 + g*4 + r
    float* base = pacc + (size_t)ch * DD * BTOT + rbase + g * 4;
    *reinterpret_cast<f32x4*>(base + (size_t)(l15) * BTOT)      = a00;
    *reinterpret_cast<f32x4*>(base + (size_t)(16 + l15) * BTOT) = a01;
    *reinterpret_cast<f32x4*>(base + (size_t)(32 + l15) * BTOT) = a02;
    *reinterpret_cast<f32x4*>(base + (size_t)(48 + l15) * BTOT) = a03;
    float* base1 = base + 16;
    *reinterpret_cast<f32x4*>(base1 + (size_t)(l15) * BTOT)      = a10;
    *reinterpret_cast<f32x4*>(base1 + (size_t)(16 + l15) * BTOT) = a11;
    *reinterpret_cast<f32x4*>(base1 + (size_t)(32 + l15) * BTOT) = a12;
    *reinterpret_cast<f32x4*>(base1 + (size_t)(48 + l15) * BTOT) = a13;
}

// ---------------- combine ----------------

__global__ __launch_bounds__(256)
void epmem_combine(const float* __restrict__ pl,
                   const float* __restrict__ pacc,
                   float* __restrict__ out,
                   int split)
{
    int t = blockIdx.x * 256 + threadIdx.x;
    if (t >= DD * BTOT) return;
    int d = t >> 10;
    int b = t & 1023;
    float ls = 0.0f;
    for (int ch = 0; ch < split; ++ch) ls += pl[(size_t)ch * BTOT + b];
    float v = 0.0f;
    for (int ch = 0; ch < split; ++ch) v += pacc[((size_t)ch * DD + d) * BTOT + b];
    out[(size_t)b * DD + d] = v / ls;
}

extern "C" void kernel_launch(void* const* d_in, const int* in_sizes, int n_in,
                              void* d_out, int out_size, void* d_ws, size_t ws_size,
                              hipStream_t stream)
{
    const float* q    = (const float*)d_in[0];
    const float* ctx  = (const float*)d_in[1];
    const float* K    = (const float*)d_in[2];
    const float* V    = (const float*)d_in[3];
    const float* CT   = (const float*)d_in[4];
    const float* TS   = (const float*)d_in[5];
    const int*   mask = (const int*)d_in[6];

    // ws layout
    char* wsb = (char*)d_ws;
    unsigned short* Qc = (unsigned short*)(wsb);                          // 1024*96*2        = 196608
    unsigned short* KC = (unsigned short*)(wsb + 196608);                 // (65536+32)*96*2  = 12589056 (32 pad rows)
    unsigned short* Vt = (unsigned short*)(wsb + 196608 + 12589056);      // 64*65536*2       = 8388608
    size_t fixed = 196608 + 12589056 + 8388608;                           // 21174272

    size_t chunk = (size_t)BTOT * (DD + 1) * sizeof(float);               // 266240
    int SPLIT = (int)((ws_size - fixed) / chunk);
    if (SPLIT > 64) SPLIT = 64;
    SPLIT &= ~7;                       // multiple of 8 (swizzle + sizing)
    if (SPLIT < 8) SPLIT = 8;

    float* pl   = (float*)(wsb + fixed);                 // [SPLIT][1024]
    float* pacc = pl + (size_t)SPLIT * BTOT;             // [SPLIT][64][1024]

    int mper = ((MTOT + SPLIT - 1) / SPLIT + 31) & ~31;  // multiple of 32

    prep_qc<<<(BTOT * 96 + 255) / 256, 256, 0, stream>>>(q, ctx, Qc);
    prep_kc<<<(MTOT * 96) / 192, 192, 0, stream>>>(K, CT, TS, mask, KC);
    prep_vt<<<MTOT / 64, 256, 0, stream>>>(V, Vt);

    int NB = 8 * SPLIT;
    epmem_mfma<<<NB, 256, 0, stream>>>(Qc, KC, Vt, pl, pacc, mper, NB);

    epmem_combine<<<(DD * BTOT + 255) / 256, 256, 0, stream>>>(pl, pacc, (float*)d_out, SPLIT);
}

// Round 6
// 86.984 us; speedup vs baseline: 8.2768x; 1.3764x over previous
//
#include <hip/hip_runtime.h>

typedef float f32x4 __attribute__((ext_vector_type(4)));
typedef __bf16 bf16x8 __attribute__((ext_vector_type(8)));
typedef unsigned int u32;
typedef unsigned short u16;

#define MTOT 65536
#define BTOT 1024
#define DD 64
#define MFMA __builtin_amdgcn_mfma_f32_16x16x32_bf16

__device__ __forceinline__ u16 f2bf(float f) {
    u32 u = __float_as_uint(f);
    return (u16)((u + 0x7FFFu + ((u >> 16) & 1u)) >> 16);
}
__device__ __forceinline__ bf16x8 ldg8(const u16* p) { return *reinterpret_cast<const bf16x8*>(p); }

__device__ __forceinline__ void glds16(const void* g, void* l) {
    __builtin_amdgcn_global_load_lds((const __attribute__((address_space(1))) u32*)g,
                                     (__attribute__((address_space(3))) u32*)l, 16, 0, 0);
}

// ---------------- precompute: Qc[1024][96] and KC[65536][96] bf16, fused ----------------
__global__ __launch_bounds__(256)
void prep_rows(const float* __restrict__ q, const float* __restrict__ ctx,
               const float* __restrict__ K, const float* __restrict__ CT,
               const float* __restrict__ TS, const int* __restrict__ mask,
               u16* __restrict__ Qc, u16* __restrict__ KCw)
{
    int gid = blockIdx.x * 256 + threadIdx.x;          // (M+B)*24 quads, exact
    int row = gid / 24, gq = gid - row * 24;
    bool isQ = row >= MTOT;
    int m = isQ ? row - MTOT : row;
    float4 v = {0.f, 0.f, 0.f, 0.f};
    if (gq < 16) {
        v = *reinterpret_cast<const float4*>((isQ ? q : K) + (size_t)m * 64 + gq * 4);
    } else if (gq < 20) {
        v = *reinterpret_cast<const float4*>((isQ ? ctx : CT) + (size_t)m * 16 + (gq - 16) * 4);
        if (isQ) { v.x *= 0.5f; v.y *= 0.5f; v.z *= 0.5f; v.w *= 0.5f; }
    } else if (gq == 20) {
        v.x = isQ ? 1.0f : (mask[m] ? 0.3f * __expf(-0.1f * (1000.0f - TS[m])) : -100.0f);
    }
    ushort4 o = {f2bf(v.x), f2bf(v.y), f2bf(v.z), f2bf(v.w)};
    u16* dst = (isQ ? Qc : KCw) + (size_t)m * 96 + gq * 4;
    *reinterpret_cast<ushort4*>(dst) = o;
}

// ---------------- precompute: Vt[64][MTOT] bf16, transposed, 32-group col-interleaved ----------------
__global__ __launch_bounds__(256)
void prep_vt(const float* __restrict__ V, u16* __restrict__ Vt)
{
    __shared__ u16 L[64][68];
    const int m0 = blockIdx.x * 64, t = threadIdx.x;
#pragma unroll
    for (int p = 0; p < 4; ++p) {
        int fi = t + p * 256;              // float4 index 0..1023
        int mi = fi >> 4, di = (fi & 15) << 2;
        float4 v = *reinterpret_cast<const float4*>(V + (size_t)(m0 + mi) * 64 + di);
        ushort4 o = {f2bf(v.x), f2bf(v.y), f2bf(v.z), f2bf(v.w)};
        *reinterpret_cast<ushort4*>(&L[mi][di]) = o;
    }
    __syncthreads();
    const int d = t >> 2, seg = t & 3;
    u32 pk[8];
#pragma unroll
    for (int pr = 0; pr < 8; ++pr) {
        int c0 = seg * 16 + pr * 2;
        int g32 = c0 >> 5;
        int i0 = c0 & 31, i1 = (c0 + 1) & 31;
        int mp0 = g32 * 32 + (i0 >> 1) + (i0 & 1) * 16;   // col interleave: c=(m'&15)*2+(m'>>4)
        int mp1 = g32 * 32 + (i1 >> 1) + (i1 & 1) * 16;
        pk[pr] = (u32)L[mp0][d] | ((u32)L[mp1][d] << 16);
    }
    uint4 A = {pk[0], pk[1], pk[2], pk[3]}, B4 = {pk[4], pk[5], pk[6], pk[7]};
    u16* dst = Vt + (size_t)d * MTOT + m0 + seg * 16;
    *reinterpret_cast<uint4*>(dst)     = A;
    *reinterpret_cast<uint4*>(dst + 8) = B4;
}

// ---------------- main: LDS-staged double-buffered flash-MFMA ----------------
__global__ __launch_bounds__(256, 2)
void epmem_mfma(const u16* __restrict__ Qc, const u16* __restrict__ KCg,
                const u16* __restrict__ Vtg,
                float* __restrict__ pl, float* __restrict__ pacc,
                int mper, int NB)
{
    __shared__ __align__(16) u16 KCs[2][64 * 128];   // 32 KB: [m 64][chunk-swizzled 256B rows]
    __shared__ __align__(16) u16 Vts[2][64 * 64];    // 16 KB: [d 64][chunk-swizzled 128B rows]
    __shared__ __align__(16) u16 Pb[4][32 * 32];     //  8 KB: per-wave [32 b][32 m' interleaved]

    const int tid = threadIdx.x;
    const int w = tid >> 6, lane = tid & 63;
    const int l15 = lane & 15, g = lane >> 4;
    const int xr = l15 & 7;

    const int bid = blockIdx.x;
    const int o = (bid & 7) * (NB >> 3) + (bid >> 3);     // XCD-bijective (NB % 8 == 0)
    const int rt = o & 7, ch = o >> 3;
    const int rbase = rt * 128 + w * 32;

    // Q fragments (2 row-frags x 3 k-chunks), read once
    const u16* q0 = Qc + (size_t)(rbase + l15) * 96 + g * 8;
    const bf16x8 qf00 = ldg8(q0), qf01 = ldg8(q0 + 32), qf02 = ldg8(q0 + 64);
    const u16* q1 = q0 + 16 * 96;
    const bf16x8 qf10 = ldg8(q1), qf11 = ldg8(q1 + 32), qf12 = ldg8(q1 + 64);

    const int m0 = ch * mper;
    const int m1 = (m0 + mper < MTOT) ? (m0 + mper) : MTOT;
    const int ntiles = (m1 > m0) ? ((m1 - m0) >> 6) : 0;

    // per-lane global byte offsets for staging (inverse-swizzled source, linear LDS dest)
    int kgo[4];
#pragma unroll
    for (int i = 0; i < 4; ++i) {
        int ol = w * 4096 + i * 1024 + lane * 16;
        int row = ol >> 8, c = (ol >> 4) & 15;
        int u = c ^ (row & 7); if (u >= 12) u = 0;   // chunks >=12 are never-read pad
        kgo[i] = row * 192 + u * 16;
    }
    int vgo[2];
#pragma unroll
    for (int i = 0; i < 2; ++i) {
        int ol = w * 2048 + i * 1024 + lane * 16;
        int row = ol >> 7, c = (ol >> 4) & 7;
        int u = c ^ (row & 7);
        vgo[i] = row * (MTOT * 2) + u * 16;
    }

    f32x4 a00 = {0,0,0,0}, a01 = {0,0,0,0}, a02 = {0,0,0,0}, a03 = {0,0,0,0};
    f32x4 a10 = {0,0,0,0}, a11 = {0,0,0,0}, a12 = {0,0,0,0}, a13 = {0,0,0,0};
    float ls[8] = {0,0,0,0,0,0,0,0};

    if (ntiles > 0) {   // prologue stage tile 0
        const char* kb = (const char*)KCg + (size_t)m0 * 192;
        const char* vb = (const char*)Vtg + (size_t)m0 * 2;
#pragma unroll
        for (int i = 0; i < 4; ++i) glds16(kb + kgo[i], (char*)KCs[0] + w * 4096 + i * 1024);
#pragma unroll
        for (int i = 0; i < 2; ++i) glds16(vb + vgo[i], (char*)Vts[0] + w * 2048 + i * 1024);
    }
    __syncthreads();    // drains vmcnt(0): tile 0 resident

    int cur = 0;
    for (int t = 0; t < ntiles; ++t) {
        if (t + 1 < ntiles) {   // fire-and-forget stage of next tile (in flight across compute)
            int mt = m0 + ((t + 1) << 6);
            const char* kb = (const char*)KCg + (size_t)mt * 192;
            const char* vb = (const char*)Vtg + (size_t)mt * 2;
            int nb = cur ^ 1;
#pragma unroll
            for (int i = 0; i < 4; ++i) glds16(kb + kgo[i], (char*)KCs[nb] + w * 4096 + i * 1024);
#pragma unroll
            for (int i = 0; i < 2; ++i) glds16(vb + vgo[i], (char*)Vts[nb] + w * 2048 + i * 1024);
        }
        const char* kcb = (const char*)KCs[cur];
        const char* vtb = (const char*)Vts[cur];
        char* pbw = (char*)Pb[w];

#pragma unroll
        for (int j = 0; j < 2; ++j) {           // two 32-m steps per 64-m tile
            bf16x8 kf[2][3];
#pragma unroll
            for (int s = 0; s < 2; ++s)
#pragma unroll
                for (int ks = 0; ks < 3; ++ks) {
                    int row = j * 32 + s * 16 + l15;
                    kf[s][ks] = *reinterpret_cast<const bf16x8*>(kcb + row * 256 + (((ks * 4 + g) ^ xr) << 4));
                }
            bf16x8 vf[4];
#pragma unroll
            for (int d4 = 0; d4 < 4; ++d4) {
                int row = d4 * 16 + l15;
                vf[d4] = *reinterpret_cast<const bf16x8*>(vtb + row * 128 + (((j * 4 + g) ^ xr) << 4));
            }

            f32x4 S00 = {0,0,0,0}, S01 = {0,0,0,0}, S10 = {0,0,0,0}, S11 = {0,0,0,0};
            S00 = MFMA(qf00, kf[0][0], S00,0,0,0); S00 = MFMA(qf01, kf[0][1], S00,0,0,0); S00 = MFMA(qf02, kf[0][2], S00,0,0,0);
            S01 = MFMA(qf00, kf[1][0], S01,0,0,0); S01 = MFMA(qf01, kf[1][1], S01,0,0,0); S01 = MFMA(qf02, kf[1][2], S01,0,0,0);
            S10 = MFMA(qf10, kf[0][0], S10,0,0,0); S10 = MFMA(qf11, kf[0][1], S10,0,0,0); S10 = MFMA(qf12, kf[0][2], S10,0,0,0);
            S11 = MFMA(qf10, kf[1][0], S11,0,0,0); S11 = MFMA(qf11, kf[1][1], S11,0,0,0); S11 = MFMA(qf12, kf[1][2], S11,0,0,0);

#pragma unroll
            for (int r = 0; r < 4; ++r) {
                float p00 = __expf(S00[r]), p01 = __expf(S01[r]);
                float p10 = __expf(S10[r]), p11 = __expf(S11[r]);
                ls[r]     += p00 + p01;
                ls[4 + r] += p10 + p11;
                int row0 = g * 4 + r, row1 = 16 + g * 4 + r;   // row&3 == r for both
                u32 w0 = (u32)f2bf(p00) | ((u32)f2bf(p01) << 16);
                u32 w1 = (u32)f2bf(p10) | ((u32)f2bf(p11) << 16);
                *(u32*)(pbw + row0 * 64 + ((((l15 >> 2) ^ r) << 4) | ((l15 & 3) << 2))) = w0;
                *(u32*)(pbw + row1 * 64 + ((((l15 >> 2) ^ r) << 4) | ((l15 & 3) << 2))) = w1;
            }
            bf16x8 pa0 = *reinterpret_cast<const bf16x8*>(pbw + l15 * 64        + ((g ^ (l15 & 3)) << 4));
            bf16x8 pa1 = *reinterpret_cast<const bf16x8*>(pbw + (16 + l15) * 64 + ((g ^ (l15 & 3)) << 4));

            a00 = MFMA(pa0, vf[0], a00,0,0,0); a01 = MFMA(pa0, vf[1], a01,0,0,0);
            a02 = MFMA(pa0, vf[2], a02,0,0,0); a03 = MFMA(pa0, vf[3], a03,0,0,0);
            a10 = MFMA(pa1, vf[0], a10,0,0,0); a11 = MFMA(pa1, vf[1], a11,0,0,0);
            a12 = MFMA(pa1, vf[2], a12,0,0,0); a13 = MFMA(pa1, vf[3], a13,0,0,0);
        }
        __syncthreads();    // drains vmcnt -> next tile resident; everyone done with cur
        cur ^= 1;
    }

    // lsum reduce over the 16 m'-lanes
#pragma unroll
    for (int i = 0; i < 8; ++i) {
        float v = ls[i];
        v += __shfl_xor(v, 1, 16); v += __shfl_xor(v, 2, 16);
        v += __shfl_xor(v, 4, 16); v += __shfl_xor(v, 8, 16);
        ls[i] = v;
    }
    if (l15 == 0) {
        f32x4 s0 = {ls[0], ls[1], ls[2], ls[3]};
        f32x4 s1 = {ls[4], ls[5], ls[6], ls[7]};
        *reinterpret_cast<f32x4*>(pl + (size_t)ch * BTOT + rbase + g * 4)      = s0;
        *reinterpret_cast<f32x4*>(pl + (size_t)ch * BTOT + rbase + 16 + g * 4) = s1;
    }
    // pacc[ch][d][b]: lane col d = d4*16+l15; rows b = rbase + f*16 + g*4 + r
    float* b0 = pacc + ((size_t)ch * DD + l15) * BTOT + rbase + g * 4;
    *reinterpret_cast<f32x4*>(b0 + (size_t)0  * BTOT) = a00;
    *reinterpret_cast<f32x4*>(b0 + (size_t)16 * BTOT) = a01;
    *reinterpret_cast<f32x4*>(b0 + (size_t)32 * BTOT) = a02;
    *reinterpret_cast<f32x4*>(b0 + (size_t)48 * BTOT) = a03;
    float* b1 = b0 + 16;
    *reinterpret_cast<f32x4*>(b1 + (size_t)0  * BTOT) = a10;
    *reinterpret_cast<f32x4*>(b1 + (size_t)16 * BTOT) = a11;
    *reinterpret_cast<f32x4*>(b1 + (size_t)32 * BTOT) = a12;
    *reinterpret_cast<f32x4*>(b1 + (size_t)48 * BTOT) = a13;
}

// ---------------- combine ----------------
__global__ __launch_bounds__(256)
void epmem_combine(const float* __restrict__ pl,
                   const float* __restrict__ pacc,
                   float* __restrict__ out, int split)
{
    int t = blockIdx.x * 256 + threadIdx.x;
    if (t >= DD * BTOT) return;
    int d = t >> 10;
    int b = t & 1023;
    float lssum = 0.0f;
    for (int ch = 0; ch < split; ++ch) lssum += pl[(size_t)ch * BTOT + b];
    float v = 0.0f;
    for (int ch = 0; ch < split; ++ch) v += pacc[((size_t)ch * DD + d) * BTOT + b];
    out[(size_t)b * DD + d] = v / lssum;
}

extern "C" void kernel_launch(void* const* d_in, const int* in_sizes, int n_in,
                              void* d_out, int out_size, void* d_ws, size_t ws_size,
                              hipStream_t stream)
{
    const float* q    = (const float*)d_in[0];
    const float* ctx  = (const float*)d_in[1];
    const float* K    = (const float*)d_in[2];
    const float* V    = (const float*)d_in[3];
    const float* CT   = (const float*)d_in[4];
    const float* TS   = (const float*)d_in[5];
    const int*   mask = (const int*)d_in[6];

    char* wsb = (char*)d_ws;
    u16* Qc = (u16*)(wsb);                                // 1024*96*2   = 196608
    u16* KC = (u16*)(wsb + 196608);                       // 65536*96*2  = 12582912
    u16* Vt = (u16*)(wsb + 196608 + 12582912);            // 64*65536*2  = 8388608
    size_t fixed = 196608 + 12582912 + 8388608;           // 21168128

    size_t chunk = (size_t)BTOT * (DD + 1) * sizeof(float);   // 266240
    int SPLIT = (int)((ws_size - fixed) / chunk);
    if (SPLIT > 64) SPLIT = 64;
    SPLIT &= ~7;
    if (SPLIT < 8) SPLIT = 8;

    float* pl   = (float*)(wsb + fixed);                  // [SPLIT][1024]
    float* pacc = pl + (size_t)SPLIT * BTOT;              // [SPLIT][64][1024]

    int mper = ((MTOT + SPLIT - 1) / SPLIT + 63) & ~63;   // multiple of 64

    prep_rows<<<(MTOT + BTOT) * 24 / 256, 256, 0, stream>>>(q, ctx, K, CT, TS, mask, Qc, KC);
    prep_vt<<<MTOT / 64, 256, 0, stream>>>(V, Vt);

    int NB = 8 * SPLIT;
    epmem_mfma<<<NB, 256, 0, stream>>>(Qc, KC, Vt, pl, pacc, mper, NB);

    epmem_combine<<<(DD * BTOT + 255) / 256, 256, 0, stream>>>(pl, pacc, (float*)d_out, SPLIT);
}